// Round 1
// baseline (250.671 us; speedup 1.0000x reference)
//
#include <hip/hip_runtime.h>
#include <hip/hip_bf16.h>
#include <stdint.h>

typedef float f32x16 __attribute__((ext_vector_type(16)));
typedef float f32x4  __attribute__((ext_vector_type(4)));
typedef short s16x8  __attribute__((ext_vector_type(8)));

#define HWSZ   4096
#define NBATCH 4

__device__ __forceinline__ unsigned short f2bf(float f) {
    unsigned u = __builtin_bit_cast(unsigned, f);
    u += 0x7FFFu + ((u >> 16) & 1u);          // RTNE
    return (unsigned short)(u >> 16);
}
__device__ __forceinline__ unsigned pack2bf(float lo, float hi) {
    return (unsigned)f2bf(lo) | ((unsigned)f2bf(hi) << 16);
}

// ---------------- Kernel 1: projections ----------------
// xq = x@W1 + b1 -> d_out (f32 residual) + xq_bf (bf16)
// yk = y@W2 + b2 -> yk_bf (bf16, [b][j][f]) + ykT_bf (bf16, [b][f][j])
__global__ __launch_bounds__(256, 1) void proj_kernel(
    const float* __restrict__ x, const float* __restrict__ y,
    const float* __restrict__ W1, const float* __restrict__ b1,
    const float* __restrict__ W2, const float* __restrict__ b2,
    float* __restrict__ xq_f32,
    unsigned short* __restrict__ xq_bf,
    unsigned short* __restrict__ yk_bf,
    unsigned short* __restrict__ ykT_bf)
{
    int idx  = blockIdx.x * 256 + threadIdx.x;   // 2,097,152 total
    int cidx = idx & 127;
    int r    = idx >> 7;
    const float* xr = x + ((size_t)r << 7);
    const float* yr = y + ((size_t)r << 7);
    float a1 = 0.f, a2 = 0.f;
    #pragma unroll 8
    for (int k = 0; k < 128; ++k) {
        a1 = fmaf(xr[k], W1[(k << 7) + cidx], a1);
        a2 = fmaf(yr[k], W2[(k << 7) + cidx], a2);
    }
    a1 += b1[cidx];
    a2 += b2[cidx];
    xq_f32[idx] = a1;
    xq_bf[idx]  = f2bf(a1);
    yk_bf[idx]  = f2bf(a2);
    int bb = r >> 12, j = r & (HWSZ - 1);
    ykT_bf[(((size_t)bb << 7) + cidx) * HWSZ + j] = f2bf(a2);
}

// ---------------- Kernel 2: sigmoid cross-attention ----------------
// out[b][q][f] = sum_j sigmoid(yk[q].xq[j]) * yk[j][f]  (+ xq residual if !SPLIT)
template<bool SPLIT>
__global__ __launch_bounds__(256, 1) void attn_kernel(
    const unsigned short* __restrict__ Kbf,   // xq_bf  [b][j][128]
    const unsigned short* __restrict__ Qbf,   // yk_bf  [b][q][128]
    const unsigned short* __restrict__ Vtbf,  // ykT_bf [b][128][4096]
    const float* resid,                       // xq f32 (d_out), used when !SPLIT
    float* outp)                              // d_out (!SPLIT) or partials base (SPLIT)
{
    __shared__ unsigned short Klds[64][136];  // K-tile, +8 pad (272B stride)
    __shared__ unsigned short Vlds[128][72];  // V^T-tile, +8 pad (144B stride)
    __shared__ unsigned short Plds[64][72];   // P[q][j] bf16, +8 pad

    const int t    = threadIdx.x;
    const int lane = t & 63;
    const int w    = t >> 6;
    const int wa   = w >> 1;   // S': j-half   | PV: q-half
    const int wb   = w & 1;    // S': q-half   | PV: f-half
    const int l31  = lane & 31;
    const int g    = lane >> 5;

    int bid = blockIdx.x;
    int half = 0;
    if (SPLIT) { half = bid >> 8; bid &= 255; }
    const int b      = bid >> 6;
    const int qb     = (bid & 63) * 64;
    const int jBegin = half * (HWSZ / 2);
    const int jEnd   = jBegin + (SPLIT ? HWSZ / 2 : HWSZ);

    // Q fragments in registers: lane holds Q[qb+32*wb+l31][fs*16 + g*8 + i]
    s16x8 qfrag[8];
    {
        const unsigned short* qp =
            Qbf + (((size_t)(b * HWSZ + qb + 32 * wb + l31)) << 7) + g * 8;
        #pragma unroll
        for (int fs = 0; fs < 8; ++fs)
            qfrag[fs] = *(const s16x8*)(qp + fs * 16);
    }

    f32x16 acc0, acc1;
    #pragma unroll
    for (int i = 0; i < 16; ++i) { acc0[i] = 0.f; acc1[i] = 0.f; }

    const unsigned short* Kbase = Kbf  + (((size_t)b * HWSZ) << 7);
    const unsigned short* Vbase = Vtbf + (((size_t)b) << 7) * HWSZ;

    for (int j0 = jBegin; j0 < jEnd; j0 += 64) {
        // ---- stage K (64x128) and V^T (128x64) into LDS ----
        #pragma unroll
        for (int c = 0; c < 4; ++c) {
            int lin = t + 256 * c;                 // 1024 16B-chunks
            int row = lin >> 4, col = (lin & 15) << 3;
            *(s16x8*)(&Klds[row][col]) =
                *(const s16x8*)(Kbase + (((size_t)(j0 + row)) << 7) + col);
        }
        #pragma unroll
        for (int c = 0; c < 4; ++c) {
            int lin = t + 256 * c;
            int f = lin >> 3, jj = (lin & 7) << 3;
            *(s16x8*)(&Vlds[f][jj]) =
                *(const s16x8*)(Vbase + (size_t)f * HWSZ + j0 + jj);
        }
        __syncthreads();

        // ---- S' = K . Q^T : 32x32 per wave (swapped so j is reg-local) ----
        f32x16 s;
        #pragma unroll
        for (int i = 0; i < 16; ++i) s[i] = 0.f;
        #pragma unroll
        for (int fs = 0; fs < 8; ++fs) {
            s16x8 kf = *(const s16x8*)(&Klds[32 * wa + l31][fs * 16 + g * 8]);
            s = __builtin_amdgcn_mfma_f32_32x32x16_bf16(kf, qfrag[fs], s, 0, 0, 0);
        }
        // sigmoid, pack bf16 pairs, write P[q][j]
        #pragma unroll
        for (int rg = 0; rg < 4; ++rg) {
            float p0 = 1.f / (1.f + __expf(-s[4 * rg + 0]));
            float p1 = 1.f / (1.f + __expf(-s[4 * rg + 1]));
            float p2 = 1.f / (1.f + __expf(-s[4 * rg + 2]));
            float p3 = 1.f / (1.f + __expf(-s[4 * rg + 3]));
            int jb = 32 * wa + 8 * rg + 4 * g;
            *(uint2*)(&Plds[32 * wb + l31][jb]) =
                make_uint2(pack2bf(p0, p1), pack2bf(p2, p3));
        }
        __syncthreads();

        // ---- PV: out[q][f] += P[q][j] * V[j][f] ----
        #pragma unroll
        for (int ks = 0; ks < 4; ++ks) {
            s16x8 pf = *(const s16x8*)(&Plds[32 * wa + l31][ks * 16 + g * 8]);
            s16x8 v0 = *(const s16x8*)(&Vlds[64 * wb + l31][ks * 16 + g * 8]);
            s16x8 v1 = *(const s16x8*)(&Vlds[64 * wb + 32 + l31][ks * 16 + g * 8]);
            acc0 = __builtin_amdgcn_mfma_f32_32x32x16_bf16(pf, v0, acc0, 0, 0, 0);
            acc1 = __builtin_amdgcn_mfma_f32_32x32x16_bf16(pf, v1, acc1, 0, 0, 0);
        }
        __syncthreads();
    }

    // ---- epilogue: D row map = (r&3) + 8*(r>>2) + 4*g ----
    float* op = outp + (SPLIT ? (size_t)half * ((size_t)NBATCH * HWSZ * 128) : 0);
    #pragma unroll
    for (int r = 0; r < 16; ++r) {
        int q = qb + 32 * wa + (r & 3) + 8 * (r >> 2) + 4 * g;
        size_t o = (((size_t)(b * HWSZ + q)) << 7) + 64 * wb + l31;
        if (SPLIT) {
            op[o]      = acc0[r];
            op[o + 32] = acc1[r];
        } else {
            op[o]      = acc0[r] + resid[o];
            op[o + 32] = acc1[r] + resid[o + 32];
        }
    }
}

// ---------------- Kernel 3: partial reduce + residual (SPLIT path) ----------------
__global__ __launch_bounds__(256, 1) void reduce_kernel(
    const float* __restrict__ p0, const float* __restrict__ p1, float* outp)
{
    int i = blockIdx.x * 256 + threadIdx.x;
    f32x4 a = ((const f32x4*)p0)[i];
    f32x4 b = ((const f32x4*)p1)[i];
    f32x4 c = ((f32x4*)outp)[i];          // xq residual written by proj_kernel
    ((f32x4*)outp)[i] = a + b + c;
}

extern "C" void kernel_launch(void* const* d_in, const int* in_sizes, int n_in,
                              void* d_out, int out_size, void* d_ws, size_t ws_size,
                              hipStream_t stream) {
    const float* x  = (const float*)d_in[0];
    const float* y  = (const float*)d_in[1];
    const float* W1 = (const float*)d_in[2];
    const float* b1 = (const float*)d_in[3];
    const float* W2 = (const float*)d_in[4];
    const float* b2 = (const float*)d_in[5];
    float* out = (float*)d_out;

    const size_t NELEM = (size_t)NBATCH * HWSZ * 128;   // 2,097,152
    unsigned short* xq_bf  = (unsigned short*)d_ws;
    unsigned short* yk_bf  = xq_bf + NELEM;
    unsigned short* ykT_bf = yk_bf + NELEM;
    float* part = (float*)(ykT_bf + NELEM);
    const bool split = ws_size >= (NELEM * 2 * 3 + NELEM * 4 * 2);  // 29,360,128 B

    proj_kernel<<<(int)(NELEM / 256), 256, 0, stream>>>(
        x, y, W1, b1, W2, b2, out, xq_bf, yk_bf, ykT_bf);

    if (split) {
        attn_kernel<true><<<512, 256, 0, stream>>>(xq_bf, yk_bf, ykT_bf, out, part);
        reduce_kernel<<<(int)(NELEM / 1024), 256, 0, stream>>>(part, part + NELEM, out);
    } else {
        attn_kernel<false><<<256, 256, 0, stream>>>(xq_bf, yk_bf, ykT_bf, out, out);
    }
}

// Round 2
// 138.140 us; speedup vs baseline: 1.8146x; 1.8146x over previous
//
#include <hip/hip_runtime.h>
#include <hip/hip_bf16.h>
#include <stdint.h>

typedef float f32x16 __attribute__((ext_vector_type(16)));
typedef float f32x4  __attribute__((ext_vector_type(4)));
typedef short s16x8  __attribute__((ext_vector_type(8)));

#define HWSZ   4096
#define NBATCH 4

__device__ __forceinline__ unsigned short f2bf(float f) {
    unsigned u = __builtin_bit_cast(unsigned, f);
    u += 0x7FFFu + ((u >> 16) & 1u);          // RTNE
    return (unsigned short)(u >> 16);
}
__device__ __forceinline__ unsigned pack2bf(float lo, float hi) {
    return (unsigned)f2bf(lo) | ((unsigned)f2bf(hi) << 16);
}

// ---------------- Kernel 1: MFMA projections ----------------
// xq = x@W1 + b1 -> d_out (f32 residual) + xq_bf (bf16)
// yk = y@W2 + b2 -> yk_bf (bf16, [b][j][f]) + ykT_bf (bf16, [b][f][j])
// Grid: 256 WGs x 256 thr; WG handles 64 rows. Waves 0,1 -> xq; waves 2,3 -> yk.
__global__ __launch_bounds__(256, 1) void proj_kernel(
    const float* __restrict__ x, const float* __restrict__ y,
    const float* __restrict__ W1, const float* __restrict__ b1,
    const float* __restrict__ W2, const float* __restrict__ b2,
    float* __restrict__ xq_f32,
    unsigned short* __restrict__ xq_bf,
    unsigned short* __restrict__ yk_bf,
    unsigned short* __restrict__ ykT_bf)
{
    __shared__ unsigned short Xlds[64][136];
    __shared__ unsigned short Ylds[64][136];
    __shared__ unsigned short Tlds[128][72];   // yk^T tile [f][j], 144B stride

    const int t    = threadIdx.x;
    const int lane = t & 63;
    const int w    = t >> 6;
    const int l31  = lane & 31;
    const int g    = lane >> 5;
    const int r0   = blockIdx.x * 64;          // global row base = b*4096 + j0
    const int b    = r0 >> 12;
    const int j0   = r0 & (HWSZ - 1);

    // ---- stage x,y 64x128 tiles as bf16 ----
    #pragma unroll
    for (int i = 0; i < 8; ++i) {
        int li = t + 256 * i;                  // 0..2047 float4 chunks
        int row = li >> 5, c = (li & 31) * 4;
        float4 vx = *(const float4*)(x + (size_t)(r0 + row) * 128 + c);
        float4 vy = *(const float4*)(y + (size_t)(r0 + row) * 128 + c);
        *(uint2*)&Xlds[row][c] = make_uint2(pack2bf(vx.x, vx.y), pack2bf(vx.z, vx.w));
        *(uint2*)&Ylds[row][c] = make_uint2(pack2bf(vy.x, vy.y), pack2bf(vy.z, vy.w));
    }
    __syncthreads();

    const int m  = w >> 1;                     // 0: xq (x,W1,b1)  1: yk (y,W2,b2)
    const int fh = w & 1;                      // column half (64)
    const float* Wm = m ? W2 : W1;
    const float* bm = m ? b2 : b1;
    const unsigned short* A0 = m ? &Ylds[0][0] : &Xlds[0][0];

    f32x16 acc[2][2];                          // [row-tile][f-tile]
    #pragma unroll
    for (int i = 0; i < 16; ++i) {
        acc[0][0][i] = 0.f; acc[0][1][i] = 0.f;
        acc[1][0][i] = 0.f; acc[1][1][i] = 0.f;
    }

    #pragma unroll
    for (int ks = 0; ks < 8; ++ks) {
        // B-frags: lane l31 = col f, k = ks*16 + g*8 + i. W is [k][f] -> lane-coalesced.
        s16x8 bfr[2];
        #pragma unroll
        for (int ft = 0; ft < 2; ++ft) {
            const float* wp = Wm + (size_t)(ks * 16 + g * 8) * 128 + fh * 64 + ft * 32 + l31;
            #pragma unroll
            for (int i = 0; i < 8; ++i)
                bfr[ft][i] = (short)f2bf(wp[(size_t)i * 128]);
        }
        #pragma unroll
        for (int rt = 0; rt < 2; ++rt) {
            s16x8 af = *(const s16x8*)(A0 + (size_t)(rt * 32 + l31) * 136 + ks * 16 + g * 8);
            acc[rt][0] = __builtin_amdgcn_mfma_f32_32x32x16_bf16(af, bfr[0], acc[rt][0], 0, 0, 0);
            acc[rt][1] = __builtin_amdgcn_mfma_f32_32x32x16_bf16(af, bfr[1], acc[rt][1], 0, 0, 0);
        }
    }

    const float bias_v[2] = { bm[fh * 64 + l31], bm[fh * 64 + 32 + l31] };

    // C layout: col f = fh*64 + ft*32 + l31 ; row = rt*32 + (r&3) + 8*(r>>2) + 4*g
    if (m == 0) {
        #pragma unroll
        for (int rt = 0; rt < 2; ++rt)
        #pragma unroll
        for (int ft = 0; ft < 2; ++ft) {
            int f = fh * 64 + ft * 32 + l31;
            #pragma unroll
            for (int r = 0; r < 16; ++r) {
                int row = rt * 32 + (r & 3) + 8 * (r >> 2) + 4 * g;
                float v = acc[rt][ft][r] + bias_v[ft];
                size_t o = (size_t)(r0 + row) * 128 + f;
                xq_f32[o] = v;
                xq_bf[o]  = f2bf(v);
            }
        }
    } else {
        #pragma unroll
        for (int rt = 0; rt < 2; ++rt)
        #pragma unroll
        for (int ft = 0; ft < 2; ++ft) {
            int f = fh * 64 + ft * 32 + l31;
            #pragma unroll
            for (int rg = 0; rg < 4; ++rg) {
                float p0 = acc[rt][ft][4 * rg + 0] + bias_v[ft];
                float p1 = acc[rt][ft][4 * rg + 1] + bias_v[ft];
                float p2 = acc[rt][ft][4 * rg + 2] + bias_v[ft];
                float p3 = acc[rt][ft][4 * rg + 3] + bias_v[ft];
                int jb = rt * 32 + 8 * rg + 4 * g;           // rows jb..jb+3
                *(uint2*)&Tlds[f][jb] = make_uint2(pack2bf(p0, p1), pack2bf(p2, p3));
                size_t o = (size_t)(r0 + jb) * 128 + f;
                yk_bf[o]       = f2bf(p0);
                yk_bf[o + 128] = f2bf(p1);
                yk_bf[o + 256] = f2bf(p2);
                yk_bf[o + 384] = f2bf(p3);
            }
        }
    }
    __syncthreads();

    // ---- cooperative ykT store: each 64B line written whole ----
    {
        int f  = t >> 1;
        int jh = (t & 1) * 32;
        unsigned short* dst = ykT_bf + ((size_t)(b * 128 + f)) * HWSZ + j0 + jh;
        #pragma unroll
        for (int c = 0; c < 4; ++c)
            *(s16x8*)(dst + c * 8) = *(const s16x8*)&Tlds[f][jh + c * 8];
    }
}

// ---------------- Kernel 2: sigmoid cross-attention ----------------
// out[b][q][f] = sum_j sigmoid(yk[q].xq[j]) * yk[j][f]  (+ xq residual if !SPLIT)
template<bool SPLIT>
__global__ __launch_bounds__(256, 1) void attn_kernel(
    const unsigned short* __restrict__ Kbf,   // xq_bf  [b][j][128]
    const unsigned short* __restrict__ Qbf,   // yk_bf  [b][q][128]
    const unsigned short* __restrict__ Vtbf,  // ykT_bf [b][128][4096]
    const float* resid,                       // xq f32 (d_out), used when !SPLIT
    float* outp)                              // d_out (!SPLIT) or partials base (SPLIT)
{
    __shared__ unsigned short Klds[64][136];  // K-tile, +8 pad (272B stride)
    __shared__ unsigned short Vlds[128][72];  // V^T-tile, +8 pad (144B stride)
    __shared__ unsigned short Plds[64][72];   // P[q][j] bf16, +8 pad

    const int t    = threadIdx.x;
    const int lane = t & 63;
    const int w    = t >> 6;
    const int wa   = w >> 1;   // S': j-half   | PV: q-half
    const int wb   = w & 1;    // S': q-half   | PV: f-half
    const int l31  = lane & 31;
    const int g    = lane >> 5;

    int bid = blockIdx.x;
    int half = 0;
    if (SPLIT) { half = bid >> 8; bid &= 255; }
    const int b      = bid >> 6;
    const int qb     = (bid & 63) * 64;
    const int jBegin = half * (HWSZ / 2);
    const int jEnd   = jBegin + (SPLIT ? HWSZ / 2 : HWSZ);

    // Q fragments in registers: lane holds Q[qb+32*wb+l31][fs*16 + g*8 + i]
    s16x8 qfrag[8];
    {
        const unsigned short* qp =
            Qbf + (((size_t)(b * HWSZ + qb + 32 * wb + l31)) << 7) + g * 8;
        #pragma unroll
        for (int fs = 0; fs < 8; ++fs)
            qfrag[fs] = *(const s16x8*)(qp + fs * 16);
    }

    f32x16 acc0, acc1;
    #pragma unroll
    for (int i = 0; i < 16; ++i) { acc0[i] = 0.f; acc1[i] = 0.f; }

    const unsigned short* Kbase = Kbf  + (((size_t)b * HWSZ) << 7);
    const unsigned short* Vbase = Vtbf + (((size_t)b) << 7) * HWSZ;

    for (int j0 = jBegin; j0 < jEnd; j0 += 64) {
        // ---- stage K (64x128) and V^T (128x64) into LDS ----
        #pragma unroll
        for (int c = 0; c < 4; ++c) {
            int lin = t + 256 * c;                 // 1024 16B-chunks
            int row = lin >> 4, col = (lin & 15) << 3;
            *(s16x8*)(&Klds[row][col]) =
                *(const s16x8*)(Kbase + (((size_t)(j0 + row)) << 7) + col);
        }
        #pragma unroll
        for (int c = 0; c < 4; ++c) {
            int lin = t + 256 * c;
            int f = lin >> 3, jj = (lin & 7) << 3;
            *(s16x8*)(&Vlds[f][jj]) =
                *(const s16x8*)(Vbase + (size_t)f * HWSZ + j0 + jj);
        }
        __syncthreads();

        // ---- S' = K . Q^T : 32x32 per wave (swapped so j is reg-local) ----
        f32x16 s;
        #pragma unroll
        for (int i = 0; i < 16; ++i) s[i] = 0.f;
        #pragma unroll
        for (int fs = 0; fs < 8; ++fs) {
            s16x8 kf = *(const s16x8*)(&Klds[32 * wa + l31][fs * 16 + g * 8]);
            s = __builtin_amdgcn_mfma_f32_32x32x16_bf16(kf, qfrag[fs], s, 0, 0, 0);
        }
        // sigmoid, pack bf16 pairs, write P[q][j]
        #pragma unroll
        for (int rg = 0; rg < 4; ++rg) {
            float p0 = 1.f / (1.f + __expf(-s[4 * rg + 0]));
            float p1 = 1.f / (1.f + __expf(-s[4 * rg + 1]));
            float p2 = 1.f / (1.f + __expf(-s[4 * rg + 2]));
            float p3 = 1.f / (1.f + __expf(-s[4 * rg + 3]));
            int jb = 32 * wa + 8 * rg + 4 * g;
            *(uint2*)(&Plds[32 * wb + l31][jb]) =
                make_uint2(pack2bf(p0, p1), pack2bf(p2, p3));
        }
        __syncthreads();

        // ---- PV: out[q][f] += P[q][j] * V[j][f] ----
        #pragma unroll
        for (int ks = 0; ks < 4; ++ks) {
            s16x8 pf = *(const s16x8*)(&Plds[32 * wa + l31][ks * 16 + g * 8]);
            s16x8 v0 = *(const s16x8*)(&Vlds[64 * wb + l31][ks * 16 + g * 8]);
            s16x8 v1 = *(const s16x8*)(&Vlds[64 * wb + 32 + l31][ks * 16 + g * 8]);
            acc0 = __builtin_amdgcn_mfma_f32_32x32x16_bf16(pf, v0, acc0, 0, 0, 0);
            acc1 = __builtin_amdgcn_mfma_f32_32x32x16_bf16(pf, v1, acc1, 0, 0, 0);
        }
        __syncthreads();
    }

    // ---- epilogue: D row map = (r&3) + 8*(r>>2) + 4*g ----
    float* op = outp + (SPLIT ? (size_t)half * ((size_t)NBATCH * HWSZ * 128) : 0);
    #pragma unroll
    for (int r = 0; r < 16; ++r) {
        int q = qb + 32 * wa + (r & 3) + 8 * (r >> 2) + 4 * g;
        size_t o = (((size_t)(b * HWSZ + q)) << 7) + 64 * wb + l31;
        if (SPLIT) {
            op[o]      = acc0[r];
            op[o + 32] = acc1[r];
        } else {
            op[o]      = acc0[r] + resid[o];
            op[o + 32] = acc1[r] + resid[o + 32];
        }
    }
}

// ---------------- Kernel 3: partial reduce + residual (SPLIT path) ----------------
__global__ __launch_bounds__(256, 1) void reduce_kernel(
    const float* __restrict__ p0, const float* __restrict__ p1, float* outp)
{
    int i = blockIdx.x * 256 + threadIdx.x;
    f32x4 a = ((const f32x4*)p0)[i];
    f32x4 b = ((const f32x4*)p1)[i];
    f32x4 c = ((f32x4*)outp)[i];          // xq residual written by proj_kernel
    ((f32x4*)outp)[i] = a + b + c;
}

extern "C" void kernel_launch(void* const* d_in, const int* in_sizes, int n_in,
                              void* d_out, int out_size, void* d_ws, size_t ws_size,
                              hipStream_t stream) {
    const float* x  = (const float*)d_in[0];
    const float* y  = (const float*)d_in[1];
    const float* W1 = (const float*)d_in[2];
    const float* b1 = (const float*)d_in[3];
    const float* W2 = (const float*)d_in[4];
    const float* b2 = (const float*)d_in[5];
    float* out = (float*)d_out;

    const size_t NELEM = (size_t)NBATCH * HWSZ * 128;   // 2,097,152
    unsigned short* xq_bf  = (unsigned short*)d_ws;
    unsigned short* yk_bf  = xq_bf + NELEM;
    unsigned short* ykT_bf = yk_bf + NELEM;
    float* part = (float*)(ykT_bf + NELEM);
    const bool split = ws_size >= (NELEM * 2 * 3 + NELEM * 4 * 2);  // 29,360,128 B

    proj_kernel<<<(int)(NBATCH * HWSZ / 64), 256, 0, stream>>>(
        x, y, W1, b1, W2, b2, out, xq_bf, yk_bf, ykT_bf);

    if (split) {
        attn_kernel<true><<<512, 256, 0, stream>>>(xq_bf, yk_bf, ykT_bf, out, part);
        reduce_kernel<<<(int)(NELEM / 1024), 256, 0, stream>>>(part, part + NELEM, out);
    } else {
        attn_kernel<false><<<256, 256, 0, stream>>>(xq_bf, yk_bf, ykT_bf, out, out);
    }
}

// Round 3
// 77.189 us; speedup vs baseline: 3.2475x; 1.7896x over previous
//
#include <hip/hip_runtime.h>
#include <hip/hip_bf16.h>
#include <stdint.h>

typedef float f32x16 __attribute__((ext_vector_type(16)));
typedef float f32x4  __attribute__((ext_vector_type(4)));
typedef short s16x8  __attribute__((ext_vector_type(8)));
typedef unsigned int u32x4 __attribute__((ext_vector_type(4)));

#define HWSZ   4096
#define NBATCH 4

__device__ __forceinline__ unsigned short f2bf(float f) {
    unsigned u = __builtin_bit_cast(unsigned, f);
    u += 0x7FFFu + ((u >> 16) & 1u);          // RTNE
    return (unsigned short)(u >> 16);
}
__device__ __forceinline__ unsigned pack2bf(float lo, float hi) {
    return (unsigned)f2bf(lo) | ((unsigned)f2bf(hi) << 16);
}
__device__ __forceinline__ float fast_sigmoid(float x) {
    // 1/(1+e^-x): v_exp + v_rcp (approx rcp, ~1ulp — way below bf16 noise)
    return __builtin_amdgcn_rcpf(1.f + __expf(-x));
}

// ---------------- Kernel 1: MFMA projections ----------------
__global__ __launch_bounds__(256, 1) void proj_kernel(
    const float* __restrict__ x, const float* __restrict__ y,
    const float* __restrict__ W1, const float* __restrict__ b1,
    const float* __restrict__ W2, const float* __restrict__ b2,
    float* __restrict__ xq_f32,
    unsigned short* __restrict__ xq_bf,
    unsigned short* __restrict__ yk_bf,
    unsigned short* __restrict__ ykT_bf)
{
    __shared__ unsigned short Xlds[64][136];
    __shared__ unsigned short Ylds[64][136];
    __shared__ unsigned short Tlds[128][72];

    const int t    = threadIdx.x;
    const int lane = t & 63;
    const int w    = t >> 6;
    const int l31  = lane & 31;
    const int g    = lane >> 5;
    const int r0   = blockIdx.x * 64;
    const int b    = r0 >> 12;
    const int j0   = r0 & (HWSZ - 1);

    #pragma unroll
    for (int i = 0; i < 8; ++i) {
        int li = t + 256 * i;
        int row = li >> 5, c = (li & 31) * 4;
        float4 vx = *(const float4*)(x + (size_t)(r0 + row) * 128 + c);
        float4 vy = *(const float4*)(y + (size_t)(r0 + row) * 128 + c);
        *(uint2*)&Xlds[row][c] = make_uint2(pack2bf(vx.x, vx.y), pack2bf(vx.z, vx.w));
        *(uint2*)&Ylds[row][c] = make_uint2(pack2bf(vy.x, vy.y), pack2bf(vy.z, vy.w));
    }
    __syncthreads();

    const int m  = w >> 1;
    const int fh = w & 1;
    const float* Wm = m ? W2 : W1;
    const float* bm = m ? b2 : b1;
    const unsigned short* A0 = m ? &Ylds[0][0] : &Xlds[0][0];

    f32x16 acc[2][2];
    #pragma unroll
    for (int i = 0; i < 16; ++i) {
        acc[0][0][i] = 0.f; acc[0][1][i] = 0.f;
        acc[1][0][i] = 0.f; acc[1][1][i] = 0.f;
    }

    #pragma unroll
    for (int ks = 0; ks < 8; ++ks) {
        s16x8 bfr[2];
        #pragma unroll
        for (int ft = 0; ft < 2; ++ft) {
            const float* wp = Wm + (size_t)(ks * 16 + g * 8) * 128 + fh * 64 + ft * 32 + l31;
            #pragma unroll
            for (int i = 0; i < 8; ++i)
                bfr[ft][i] = (short)f2bf(wp[(size_t)i * 128]);
        }
        #pragma unroll
        for (int rt = 0; rt < 2; ++rt) {
            s16x8 af = *(const s16x8*)(A0 + (size_t)(rt * 32 + l31) * 136 + ks * 16 + g * 8);
            acc[rt][0] = __builtin_amdgcn_mfma_f32_32x32x16_bf16(af, bfr[0], acc[rt][0], 0, 0, 0);
            acc[rt][1] = __builtin_amdgcn_mfma_f32_32x32x16_bf16(af, bfr[1], acc[rt][1], 0, 0, 0);
        }
    }

    const float bias_v[2] = { bm[fh * 64 + l31], bm[fh * 64 + 32 + l31] };

    if (m == 0) {
        #pragma unroll
        for (int rt = 0; rt < 2; ++rt)
        #pragma unroll
        for (int ft = 0; ft < 2; ++ft) {
            int f = fh * 64 + ft * 32 + l31;
            #pragma unroll
            for (int r = 0; r < 16; ++r) {
                int row = rt * 32 + (r & 3) + 8 * (r >> 2) + 4 * g;
                float v = acc[rt][ft][r] + bias_v[ft];
                size_t o = (size_t)(r0 + row) * 128 + f;
                xq_f32[o] = v;
                xq_bf[o]  = f2bf(v);
            }
        }
    } else {
        #pragma unroll
        for (int rt = 0; rt < 2; ++rt)
        #pragma unroll
        for (int ft = 0; ft < 2; ++ft) {
            int f = fh * 64 + ft * 32 + l31;
            #pragma unroll
            for (int rg = 0; rg < 4; ++rg) {
                float p0 = acc[rt][ft][4 * rg + 0] + bias_v[ft];
                float p1 = acc[rt][ft][4 * rg + 1] + bias_v[ft];
                float p2 = acc[rt][ft][4 * rg + 2] + bias_v[ft];
                float p3 = acc[rt][ft][4 * rg + 3] + bias_v[ft];
                int jb = rt * 32 + 8 * rg + 4 * g;
                *(uint2*)&Tlds[f][jb] = make_uint2(pack2bf(p0, p1), pack2bf(p2, p3));
                size_t o = (size_t)(r0 + jb) * 128 + f;
                yk_bf[o]       = f2bf(p0);
                yk_bf[o + 128] = f2bf(p1);
                yk_bf[o + 256] = f2bf(p2);
                yk_bf[o + 384] = f2bf(p3);
            }
        }
    }
    __syncthreads();

    {
        int f  = t >> 1;
        int jh = (t & 1) * 32;
        unsigned short* dst = ykT_bf + ((size_t)(b * 128 + f)) * HWSZ + j0 + jh;
        #pragma unroll
        for (int c = 0; c < 4; ++c)
            *(s16x8*)(dst + c * 8) = *(const s16x8*)&Tlds[f][jh + c * 8];
    }
}

// ---------------- Kernel 2: sigmoid cross-attention ----------------
// 4 waves = (qt 0..1) x (jt 0..1). Per iter: wave computes S' tile
// [32j(jt) x 32q(qt)] (8 MFMA), in-register sigmoid+pack, cross-half shfl to
// assemble PV A-frags, PV partial over its j-half into 32q x 128f acc
// (8 MFMA). One barrier/iter, double-buffered K/V with issue-early staging.
// End: jt-pairs reduced through LDS.
#define KT_STR   136
#define VT_STR   72
#define KT_BYTES (64 * KT_STR * 2)     // 17408
#define VT_BYTES (128 * VT_STR * 2)    // 18432
#define BUF_BYTES (KT_BYTES + VT_BYTES)

template<bool SPLIT>
__global__ __launch_bounds__(256, 2) void attn_kernel(
    const unsigned short* __restrict__ Kbf,   // xq_bf  [b][j][128]
    const unsigned short* __restrict__ Qbf,   // yk_bf  [b][q][128]
    const unsigned short* __restrict__ Vtbf,  // ykT_bf [b][128][4096]
    const float* __restrict__ resid,          // xq f32 (!SPLIT)
    float* __restrict__ outp)
{
    __shared__ __align__(16) char smem[2 * BUF_BYTES];   // 71680 B

    const int t    = threadIdx.x;
    const int lane = t & 63;
    const int w    = t >> 6;
    const int qt   = w & 1;
    const int jt   = w >> 1;
    const int l31  = lane & 31;
    const int g    = lane >> 5;

    int bid = blockIdx.x;
    int half = 0;
    if (SPLIT) { half = bid >> 8; bid &= 255; }
    const int b      = bid >> 6;
    const int qb     = (bid & 63) * 64;
    const int jBegin = half * (HWSZ / 2);
    const int nt     = (SPLIT ? HWSZ / 2 : HWSZ) / 64;

    // Q fragments: lane holds Q[qb+32*qt+l31][fs*16 + g*8 + i]
    s16x8 qfrag[8];
    {
        const unsigned short* qp =
            Qbf + (((size_t)(b * HWSZ + qb + 32 * qt + l31)) << 7) + g * 8;
        #pragma unroll
        for (int fs = 0; fs < 8; ++fs)
            qfrag[fs] = *(const s16x8*)(qp + fs * 16);
    }

    f32x16 acc[4];
    #pragma unroll
    for (int ft = 0; ft < 4; ++ft)
        #pragma unroll
        for (int i = 0; i < 16; ++i) acc[ft][i] = 0.f;

    const unsigned short* Kbase = Kbf  + (((size_t)b * HWSZ) << 7);
    const unsigned short* Vbase = Vtbf + (((size_t)b) << 7) * HWSZ;

    // ---- prologue: stage tile 0 into buf 0 ----
    {
        unsigned short* Kl = (unsigned short*)smem;
        unsigned short* Vl = (unsigned short*)(smem + KT_BYTES);
        #pragma unroll
        for (int i = 0; i < 4; ++i) {
            int lin = t + 256 * i;
            int row = lin >> 4, cc = lin & 15;
            *(s16x8*)(Kl + row * KT_STR + cc * 8) =
                *(const s16x8*)(Kbase + (((size_t)(jBegin + row)) << 7) + cc * 8);
        }
        #pragma unroll
        for (int i = 0; i < 4; ++i) {
            int lin = t + 256 * i;
            int f = lin >> 3, jc = lin & 7;
            *(s16x8*)(Vl + f * VT_STR + jc * 8) =
                *(const s16x8*)(Vbase + (size_t)f * HWSZ + jBegin + jc * 8);
        }
    }
    __syncthreads();

    int c = 0;
    for (int it = 0; it < nt; ++it) {
        const bool pre = (it + 1 < nt);
        s16x8 kr[4], vr[4];
        if (pre) {                       // issue-early loads for tile it+1
            int j0n = jBegin + (it + 1) * 64;
            #pragma unroll
            for (int i = 0; i < 4; ++i) {
                int lin = t + 256 * i;
                int row = lin >> 4, cc = lin & 15;
                kr[i] = *(const s16x8*)(Kbase + (((size_t)(j0n + row)) << 7) + cc * 8);
            }
            #pragma unroll
            for (int i = 0; i < 4; ++i) {
                int lin = t + 256 * i;
                int f = lin >> 3, jc = lin & 7;
                vr[i] = *(const s16x8*)(Vbase + (size_t)f * HWSZ + j0n + jc * 8);
            }
        }

        const unsigned short* Kl = (const unsigned short*)(smem + c * BUF_BYTES);
        const unsigned short* Vl = (const unsigned short*)(smem + c * BUF_BYTES + KT_BYTES);

        // ---- QK: S'[j=32jt block][q=32qt block] ----
        f32x16 s;
        #pragma unroll
        for (int i = 0; i < 16; ++i) s[i] = 0.f;
        const unsigned short* Krow = Kl + (size_t)(32 * jt + l31) * KT_STR + g * 8;
        #pragma unroll
        for (int fs = 0; fs < 8; ++fs)
            s = __builtin_amdgcn_mfma_f32_32x32x16_bf16(
                    *(const s16x8*)(Krow + fs * 16), qfrag[fs], s, 0, 0, 0);

        // ---- sigmoid + pack (j-pairs) ----
        unsigned W0[4], W1[4];
        #pragma unroll
        for (int rg = 0; rg < 4; ++rg) {
            float p0 = fast_sigmoid(s[4 * rg + 0]);
            float p1 = fast_sigmoid(s[4 * rg + 1]);
            float p2 = fast_sigmoid(s[4 * rg + 2]);
            float p3 = fast_sigmoid(s[4 * rg + 3]);
            W0[rg] = pack2bf(p0, p1);
            W1[rg] = pack2bf(p2, p3);
        }

        // ---- PV over own j-half: A-frag via lane^32 exchange ----
        #pragma unroll
        for (int s2 = 0; s2 < 2; ++s2) {
            // own rg = 2*s2+g, send rg = 2*s2+(g^1)   (compile-time indices + select)
            unsigned o0 = g ? W0[2 * s2 + 1] : W0[2 * s2];
            unsigned o1 = g ? W1[2 * s2 + 1] : W1[2 * s2];
            unsigned t0 = g ? W0[2 * s2]     : W0[2 * s2 + 1];
            unsigned t1 = g ? W1[2 * s2]     : W1[2 * s2 + 1];
            unsigned r0 = __shfl_xor(t0, 32, 64);
            unsigned r1 = __shfl_xor(t1, 32, 64);
            u32x4 pw;
            pw[0] = g ? r0 : o0;
            pw[1] = g ? r1 : o1;
            pw[2] = g ? o0 : r0;
            pw[3] = g ? o1 : r1;
            s16x8 pf = __builtin_bit_cast(s16x8, pw);
            const int ks = 2 * jt + s2;
            #pragma unroll
            for (int ft = 0; ft < 4; ++ft) {
                s16x8 vf = *(const s16x8*)(Vl + (size_t)(32 * ft + l31) * VT_STR + ks * 16 + g * 8);
                acc[ft] = __builtin_amdgcn_mfma_f32_32x32x16_bf16(pf, vf, acc[ft], 0, 0, 0);
            }
        }

        if (pre) {                       // write-late into other buffer
            unsigned short* Kd = (unsigned short*)(smem + (c ^ 1) * BUF_BYTES);
            unsigned short* Vd = (unsigned short*)(smem + (c ^ 1) * BUF_BYTES + KT_BYTES);
            #pragma unroll
            for (int i = 0; i < 4; ++i) {
                int lin = t + 256 * i;
                *(s16x8*)(Kd + (lin >> 4) * KT_STR + (lin & 15) * 8) = kr[i];
            }
            #pragma unroll
            for (int i = 0; i < 4; ++i) {
                int lin = t + 256 * i;
                *(s16x8*)(Vd + (lin >> 3) * VT_STR + (lin & 7) * 8) = vr[i];
            }
        }
        __syncthreads();
        c ^= 1;
    }

    // ---- cross-wave (jt) pair reduction through LDS ----
    float* red = (float*)smem;                       // 32 KB, safely past last reads
    if (jt == 1) {
        #pragma unroll
        for (int ft = 0; ft < 4; ++ft)
        #pragma unroll
        for (int r = 0; r < 16; ++r) {
            int row = (r & 3) + 8 * (r >> 2) + 4 * g;
            red[qt * 4096 + row * 128 + 32 * ft + l31] = acc[ft][r];
        }
    }
    __syncthreads();
    if (jt == 0) {
        float* op = outp + (SPLIT ? (size_t)half * ((size_t)NBATCH * HWSZ * 128) : 0);
        #pragma unroll
        for (int ft = 0; ft < 4; ++ft)
        #pragma unroll
        for (int r = 0; r < 16; ++r) {
            int row = (r & 3) + 8 * (r >> 2) + 4 * g;
            float v = acc[ft][r] + red[qt * 4096 + row * 128 + 32 * ft + l31];
            int q = qb + 32 * qt + row;
            size_t o = (((size_t)(b * HWSZ + q)) << 7) + 32 * ft + l31;
            if (SPLIT) op[o] = v;
            else       op[o] = v + resid[o];
        }
    }
}

// ---------------- Kernel 3: partial reduce + residual (SPLIT path) ----------------
__global__ __launch_bounds__(256, 1) void reduce_kernel(
    const float* __restrict__ p0, const float* __restrict__ p1, float* outp)
{
    int i = blockIdx.x * 256 + threadIdx.x;
    f32x4 a = ((const f32x4*)p0)[i];
    f32x4 b = ((const f32x4*)p1)[i];
    f32x4 c = ((f32x4*)outp)[i];
    ((f32x4*)outp)[i] = a + b + c;
}

extern "C" void kernel_launch(void* const* d_in, const int* in_sizes, int n_in,
                              void* d_out, int out_size, void* d_ws, size_t ws_size,
                              hipStream_t stream) {
    const float* x  = (const float*)d_in[0];
    const float* y  = (const float*)d_in[1];
    const float* W1 = (const float*)d_in[2];
    const float* b1 = (const float*)d_in[3];
    const float* W2 = (const float*)d_in[4];
    const float* b2 = (const float*)d_in[5];
    float* out = (float*)d_out;

    const size_t NELEM = (size_t)NBATCH * HWSZ * 128;   // 2,097,152
    unsigned short* xq_bf  = (unsigned short*)d_ws;
    unsigned short* yk_bf  = xq_bf + NELEM;
    unsigned short* ykT_bf = yk_bf + NELEM;
    float* part = (float*)(ykT_bf + NELEM);
    const bool split = ws_size >= (NELEM * 2 * 3 + NELEM * 4 * 2);

    proj_kernel<<<(int)(NBATCH * HWSZ / 64), 256, 0, stream>>>(
        x, y, W1, b1, W2, b2, out, xq_bf, yk_bf, ykT_bf);

    if (split) {
        attn_kernel<true><<<512, 256, 0, stream>>>(xq_bf, yk_bf, ykT_bf, out, part);
        reduce_kernel<<<(int)(NELEM / 1024), 256, 0, stream>>>(part, part + NELEM, out);
    } else {
        attn_kernel<false><<<256, 256, 0, stream>>>(xq_bf, yk_bf, ykT_bf, out, out);
    }
}

// Round 4
// 75.368 us; speedup vs baseline: 3.3259x; 1.0242x over previous
//
#include <hip/hip_runtime.h>
#include <hip/hip_bf16.h>
#include <stdint.h>

typedef float f32x16 __attribute__((ext_vector_type(16)));
typedef float f32x4  __attribute__((ext_vector_type(4)));
typedef short s16x8  __attribute__((ext_vector_type(8)));
typedef unsigned int u32x4 __attribute__((ext_vector_type(4)));

#define HWSZ   4096
#define NBATCH 4
#define LOG2E  1.44269504088896340736f

__device__ __forceinline__ unsigned short f2bf(float f) {
    unsigned u = __builtin_bit_cast(unsigned, f);
    u += 0x7FFFu + ((u >> 16) & 1u);          // RTNE
    return (unsigned short)(u >> 16);
}
__device__ __forceinline__ unsigned cvt_pk_bf16(float lo, float hi) {
    __hip_bfloat162 h = __float22bfloat162_rn(make_float2(lo, hi));
    return *reinterpret_cast<unsigned*>(&h);   // v_cvt_pk_bf16_f32
}

// ---------------- Kernel 1: MFMA projections ----------------
// xq = x@W1 + b1 -> d_out (f32 residual) + xq_bf (bf16, PRE-SCALED by log2e: K-only)
// yk = y@W2 + b2 -> yk_bf (bf16) + ykT_bf (bf16 transposed)
__global__ __launch_bounds__(256, 1) void proj_kernel(
    const float* __restrict__ x, const float* __restrict__ y,
    const float* __restrict__ W1, const float* __restrict__ b1,
    const float* __restrict__ W2, const float* __restrict__ b2,
    float* __restrict__ xq_f32,
    unsigned short* __restrict__ xq_bf,
    unsigned short* __restrict__ yk_bf,
    unsigned short* __restrict__ ykT_bf)
{
    __shared__ unsigned short Xlds[64][136];
    __shared__ unsigned short Ylds[64][136];
    __shared__ unsigned short Tlds[128][72];

    const int t    = threadIdx.x;
    const int lane = t & 63;
    const int w    = t >> 6;
    const int l31  = lane & 31;
    const int g    = lane >> 5;
    const int r0   = blockIdx.x * 64;
    const int b    = r0 >> 12;
    const int j0   = r0 & (HWSZ - 1);

    #pragma unroll
    for (int i = 0; i < 8; ++i) {
        int li = t + 256 * i;
        int row = li >> 5, c = (li & 31) * 4;
        float4 vx = *(const float4*)(x + (size_t)(r0 + row) * 128 + c);
        float4 vy = *(const float4*)(y + (size_t)(r0 + row) * 128 + c);
        *(uint2*)&Xlds[row][c] = make_uint2(cvt_pk_bf16(vx.x, vx.y), cvt_pk_bf16(vx.z, vx.w));
        *(uint2*)&Ylds[row][c] = make_uint2(cvt_pk_bf16(vy.x, vy.y), cvt_pk_bf16(vy.z, vy.w));
    }
    __syncthreads();

    const int m  = w >> 1;
    const int fh = w & 1;
    const float* Wm = m ? W2 : W1;
    const float* bm = m ? b2 : b1;
    const unsigned short* A0 = m ? &Ylds[0][0] : &Xlds[0][0];

    f32x16 acc[2][2];
    #pragma unroll
    for (int i = 0; i < 16; ++i) {
        acc[0][0][i] = 0.f; acc[0][1][i] = 0.f;
        acc[1][0][i] = 0.f; acc[1][1][i] = 0.f;
    }

    #pragma unroll
    for (int ks = 0; ks < 8; ++ks) {
        s16x8 bfr[2];
        #pragma unroll
        for (int ft = 0; ft < 2; ++ft) {
            const float* wp = Wm + (size_t)(ks * 16 + g * 8) * 128 + fh * 64 + ft * 32 + l31;
            #pragma unroll
            for (int i = 0; i < 8; ++i)
                bfr[ft][i] = (short)f2bf(wp[(size_t)i * 128]);
        }
        #pragma unroll
        for (int rt = 0; rt < 2; ++rt) {
            s16x8 af = *(const s16x8*)(A0 + (size_t)(rt * 32 + l31) * 136 + ks * 16 + g * 8);
            acc[rt][0] = __builtin_amdgcn_mfma_f32_32x32x16_bf16(af, bfr[0], acc[rt][0], 0, 0, 0);
            acc[rt][1] = __builtin_amdgcn_mfma_f32_32x32x16_bf16(af, bfr[1], acc[rt][1], 0, 0, 0);
        }
    }

    const float bias_v[2] = { bm[fh * 64 + l31], bm[fh * 64 + 32 + l31] };

    if (m == 0) {
        #pragma unroll
        for (int rt = 0; rt < 2; ++rt)
        #pragma unroll
        for (int ft = 0; ft < 2; ++ft) {
            int f = fh * 64 + ft * 32 + l31;
            #pragma unroll
            for (int r = 0; r < 16; ++r) {
                int row = rt * 32 + (r & 3) + 8 * (r >> 2) + 4 * g;
                float v = acc[rt][ft][r] + bias_v[ft];
                size_t o = (size_t)(r0 + row) * 128 + f;
                xq_f32[o] = v;
                xq_bf[o]  = f2bf(v * LOG2E);      // K pre-scaled for exp2 sigmoid
            }
        }
    } else {
        #pragma unroll
        for (int rt = 0; rt < 2; ++rt)
        #pragma unroll
        for (int ft = 0; ft < 2; ++ft) {
            int f = fh * 64 + ft * 32 + l31;
            #pragma unroll
            for (int rg = 0; rg < 4; ++rg) {
                float p0 = acc[rt][ft][4 * rg + 0] + bias_v[ft];
                float p1 = acc[rt][ft][4 * rg + 1] + bias_v[ft];
                float p2 = acc[rt][ft][4 * rg + 2] + bias_v[ft];
                float p3 = acc[rt][ft][4 * rg + 3] + bias_v[ft];
                int jb = rt * 32 + 8 * rg + 4 * g;
                *(uint2*)&Tlds[f][jb] = make_uint2(cvt_pk_bf16(p0, p1), cvt_pk_bf16(p2, p3));
                size_t o = (size_t)(r0 + jb) * 128 + f;
                yk_bf[o]       = f2bf(p0);
                yk_bf[o + 128] = f2bf(p1);
                yk_bf[o + 256] = f2bf(p2);
                yk_bf[o + 384] = f2bf(p3);
            }
        }
    }
    __syncthreads();

    {
        int f  = t >> 1;
        int jh = (t & 1) * 32;
        unsigned short* dst = ykT_bf + ((size_t)(b * 128 + f)) * HWSZ + j0 + jh;
        #pragma unroll
        for (int c = 0; c < 4; ++c)
            *(s16x8*)(dst + c * 8) = *(const s16x8*)&Tlds[f][jh + c * 8];
    }
}

// ---------------- Kernel 2: sigmoid cross-attention ----------------
#define KT_STR   136
#define VT_STR   72
#define KT_BYTES (64 * KT_STR * 2)
#define VT_BYTES (128 * VT_STR * 2)
#define BUF_BYTES (KT_BYTES + VT_BYTES)

template<bool SPLIT>
__global__ __launch_bounds__(256, 2) void attn_kernel(
    const unsigned short* __restrict__ Kbf,   // xq_bf (log2e-scaled) [b][j][128]
    const unsigned short* __restrict__ Qbf,   // yk_bf  [b][q][128]
    const unsigned short* __restrict__ Vtbf,  // ykT_bf [b][128][4096]
    const float* __restrict__ resid,
    float* __restrict__ outp)
{
    __shared__ __align__(16) char smem[2 * BUF_BYTES];

    const int t    = threadIdx.x;
    const int lane = t & 63;
    const int w    = t >> 6;
    const int qt   = w & 1;
    const int jt   = w >> 1;
    const int l31  = lane & 31;
    const int g    = lane >> 5;

    int bid = blockIdx.x;
    int half = 0;
    if (SPLIT) { half = bid >> 8; bid &= 255; }
    const int b      = bid >> 6;
    const int qb     = (bid & 63) * 64;
    const int jBegin = half * (HWSZ / 2);
    const int nt     = (SPLIT ? HWSZ / 2 : HWSZ) / 64;

    s16x8 qfrag[8];
    {
        const unsigned short* qp =
            Qbf + (((size_t)(b * HWSZ + qb + 32 * qt + l31)) << 7) + g * 8;
        #pragma unroll
        for (int fs = 0; fs < 8; ++fs)
            qfrag[fs] = *(const s16x8*)(qp + fs * 16);
    }

    f32x16 acc[4];
    #pragma unroll
    for (int ft = 0; ft < 4; ++ft)
        #pragma unroll
        for (int i = 0; i < 16; ++i) acc[ft][i] = 0.f;

    const unsigned short* Kbase = Kbf  + (((size_t)b * HWSZ) << 7);
    const unsigned short* Vbase = Vtbf + (((size_t)b) << 7) * HWSZ;

    // strength-reduced per-thread staging pointers (advance per tile)
    const unsigned short* kSrc = Kbase + (size_t)(jBegin + (t >> 4)) * 128 + (t & 15) * 8;
    const unsigned short* vSrc = Vbase + (size_t)(t >> 3) * HWSZ + jBegin + (t & 7) * 8;
    const int kDst = (t >> 4) * KT_STR + (t & 15) * 8;   // elem offsets in tile
    const int vDst = (t >> 3) * VT_STR + (t & 7) * 8;

    // ---- prologue: stage tile 0 into buf 0 ----
    {
        unsigned short* Kl = (unsigned short*)smem;
        unsigned short* Vl = (unsigned short*)(smem + KT_BYTES);
        #pragma unroll
        for (int i = 0; i < 4; ++i)
            *(s16x8*)(Kl + kDst + i * 16 * KT_STR) = *(const s16x8*)(kSrc + (size_t)i * 2048);
        #pragma unroll
        for (int i = 0; i < 4; ++i)
            *(s16x8*)(Vl + vDst + i * 32 * VT_STR) = *(const s16x8*)(vSrc + (size_t)i * 32 * HWSZ);
    }
    __syncthreads();

    int c = 0;
    for (int it = 0; it < nt; ++it) {
        const bool pre = (it + 1 < nt);
        s16x8 kr[4], vr[4];
        if (pre) {                       // issue-early loads for tile it+1
            kSrc += 64 * 128;
            vSrc += 64;
            #pragma unroll
            for (int i = 0; i < 4; ++i)
                kr[i] = *(const s16x8*)(kSrc + (size_t)i * 2048);
            #pragma unroll
            for (int i = 0; i < 4; ++i)
                vr[i] = *(const s16x8*)(vSrc + (size_t)i * 32 * HWSZ);
        }

        const unsigned short* Kl = (const unsigned short*)(smem + c * BUF_BYTES);
        const unsigned short* Vl = (const unsigned short*)(smem + c * BUF_BYTES + KT_BYTES);

        // ---- QK: dual-chain accumulate ----
        f32x16 sa, sb;
        #pragma unroll
        for (int i = 0; i < 16; ++i) { sa[i] = 0.f; sb[i] = 0.f; }
        const unsigned short* Krow = Kl + (size_t)(32 * jt + l31) * KT_STR + g * 8;
        __builtin_amdgcn_s_setprio(1);
        #pragma unroll
        for (int fs = 0; fs < 4; ++fs) {
            sa = __builtin_amdgcn_mfma_f32_32x32x16_bf16(
                     *(const s16x8*)(Krow + fs * 16), qfrag[fs], sa, 0, 0, 0);
            sb = __builtin_amdgcn_mfma_f32_32x32x16_bf16(
                     *(const s16x8*)(Krow + (fs + 4) * 16), qfrag[fs + 4], sb, 0, 0, 0);
        }
        __builtin_amdgcn_s_setprio(0);

        // ---- sigmoid via exp2 (K pre-scaled) + cvt_pk pack ----
        unsigned W0[4], W1[4];
        #pragma unroll
        for (int rg = 0; rg < 4; ++rg) {
            float s0 = sa[4 * rg + 0] + sb[4 * rg + 0];
            float s1 = sa[4 * rg + 1] + sb[4 * rg + 1];
            float s2 = sa[4 * rg + 2] + sb[4 * rg + 2];
            float s3 = sa[4 * rg + 3] + sb[4 * rg + 3];
            float p0 = __builtin_amdgcn_rcpf(1.f + __builtin_amdgcn_exp2f(-s0));
            float p1 = __builtin_amdgcn_rcpf(1.f + __builtin_amdgcn_exp2f(-s1));
            float p2 = __builtin_amdgcn_rcpf(1.f + __builtin_amdgcn_exp2f(-s2));
            float p3 = __builtin_amdgcn_rcpf(1.f + __builtin_amdgcn_exp2f(-s3));
            W0[rg] = cvt_pk_bf16(p0, p1);
            W1[rg] = cvt_pk_bf16(p2, p3);
        }

        // ---- PV over own j-half: A-frag via lane^32 exchange ----
        #pragma unroll
        for (int s2 = 0; s2 < 2; ++s2) {
            unsigned o0 = g ? W0[2 * s2 + 1] : W0[2 * s2];
            unsigned o1 = g ? W1[2 * s2 + 1] : W1[2 * s2];
            unsigned t0 = g ? W0[2 * s2]     : W0[2 * s2 + 1];
            unsigned t1 = g ? W1[2 * s2]     : W1[2 * s2 + 1];
            unsigned r0 = __shfl_xor(t0, 32, 64);
            unsigned r1 = __shfl_xor(t1, 32, 64);
            u32x4 pw;
            pw[0] = g ? r0 : o0;
            pw[1] = g ? r1 : o1;
            pw[2] = g ? o0 : r0;
            pw[3] = g ? o1 : r1;
            s16x8 pf = __builtin_bit_cast(s16x8, pw);
            const int ks = 2 * jt + s2;
            __builtin_amdgcn_s_setprio(1);
            #pragma unroll
            for (int ft = 0; ft < 4; ++ft) {
                s16x8 vf = *(const s16x8*)(Vl + (size_t)(32 * ft + l31) * VT_STR + ks * 16 + g * 8);
                acc[ft] = __builtin_amdgcn_mfma_f32_32x32x16_bf16(pf, vf, acc[ft], 0, 0, 0);
            }
            __builtin_amdgcn_s_setprio(0);
        }

        if (pre) {                       // write-late into other buffer
            unsigned short* Kd = (unsigned short*)(smem + (c ^ 1) * BUF_BYTES);
            unsigned short* Vd = (unsigned short*)(smem + (c ^ 1) * BUF_BYTES + KT_BYTES);
            #pragma unroll
            for (int i = 0; i < 4; ++i)
                *(s16x8*)(Kd + kDst + i * 16 * KT_STR) = kr[i];
            #pragma unroll
            for (int i = 0; i < 4; ++i)
                *(s16x8*)(Vd + vDst + i * 32 * VT_STR) = vr[i];
        }
        __syncthreads();
        c ^= 1;
    }

    // ---- cross-wave (jt) pair reduction through LDS ----
    float* red = (float*)smem;
    if (jt == 1) {
        #pragma unroll
        for (int ft = 0; ft < 4; ++ft)
        #pragma unroll
        for (int r = 0; r < 16; ++r) {
            int row = (r & 3) + 8 * (r >> 2) + 4 * g;
            red[qt * 4096 + row * 128 + 32 * ft + l31] = acc[ft][r];
        }
    }
    __syncthreads();
    if (jt == 0) {
        float* op = outp + (SPLIT ? (size_t)half * ((size_t)NBATCH * HWSZ * 128) : 0);
        #pragma unroll
        for (int ft = 0; ft < 4; ++ft)
        #pragma unroll
        for (int r = 0; r < 16; ++r) {
            int row = (r & 3) + 8 * (r >> 2) + 4 * g;
            float v = acc[ft][r] + red[qt * 4096 + row * 128 + 32 * ft + l31];
            int q = qb + 32 * qt + row;
            size_t o = (((size_t)(b * HWSZ + q)) << 7) + 32 * ft + l31;
            if (SPLIT) op[o] = v;
            else       op[o] = v + resid[o];
        }
    }
}

// ---------------- Kernel 3: partial reduce + residual (SPLIT path) ----------------
__global__ __launch_bounds__(256, 1) void reduce_kernel(
    const float* __restrict__ p0, const float* __restrict__ p1, float* outp)
{
    int i = blockIdx.x * 256 + threadIdx.x;
    f32x4 a = ((const f32x4*)p0)[i];
    f32x4 b = ((const f32x4*)p1)[i];
    f32x4 c = ((f32x4*)outp)[i];
    ((f32x4*)outp)[i] = a + b + c;
}

extern "C" void kernel_launch(void* const* d_in, const int* in_sizes, int n_in,
                              void* d_out, int out_size, void* d_ws, size_t ws_size,
                              hipStream_t stream) {
    const float* x  = (const float*)d_in[0];
    const float* y  = (const float*)d_in[1];
    const float* W1 = (const float*)d_in[2];
    const float* b1 = (const float*)d_in[3];
    const float* W2 = (const float*)d_in[4];
    const float* b2 = (const float*)d_in[5];
    float* out = (float*)d_out;

    const size_t NELEM = (size_t)NBATCH * HWSZ * 128;   // 2,097,152
    unsigned short* xq_bf  = (unsigned short*)d_ws;
    unsigned short* yk_bf  = xq_bf + NELEM;
    unsigned short* ykT_bf = yk_bf + NELEM;
    float* part = (float*)(ykT_bf + NELEM);
    const bool split = ws_size >= (NELEM * 2 * 3 + NELEM * 4 * 2);

    proj_kernel<<<(int)(NBATCH * HWSZ / 64), 256, 0, stream>>>(
        x, y, W1, b1, W2, b2, out, xq_bf, yk_bf, ykT_bf);

    if (split) {
        attn_kernel<true><<<512, 256, 0, stream>>>(xq_bf, yk_bf, ykT_bf, out, part);
        reduce_kernel<<<(int)(NELEM / 1024), 256, 0, stream>>>(part, part + NELEM, out);
    } else {
        attn_kernel<false><<<256, 256, 0, stream>>>(xq_bf, yk_bf, ykT_bf, out, out);
    }
}

// Round 5
// 70.678 us; speedup vs baseline: 3.5466x; 1.0664x over previous
//
#include <hip/hip_runtime.h>
#include <hip/hip_bf16.h>
#include <stdint.h>

typedef float f32x16 __attribute__((ext_vector_type(16)));
typedef float f32x4  __attribute__((ext_vector_type(4)));
typedef short s16x8  __attribute__((ext_vector_type(8)));
typedef unsigned int u32x4 __attribute__((ext_vector_type(4)));

#define HWSZ   4096
#define NBATCH 4
#define LOG2E  1.44269504088896340736f

__device__ __forceinline__ unsigned short f2bf(float f) {
    unsigned u = __builtin_bit_cast(unsigned, f);
    u += 0x7FFFu + ((u >> 16) & 1u);          // RTNE
    return (unsigned short)(u >> 16);
}
__device__ __forceinline__ unsigned cvt_pk_bf16(float lo, float hi) {
    __hip_bfloat162 h = __float22bfloat162_rn(make_float2(lo, hi));
    return *reinterpret_cast<unsigned*>(&h);   // v_cvt_pk_bf16_f32
}

// ---------------- Kernel 1: MFMA projections ----------------
// xq = x@W1 + b1 -> d_out (f32 residual) + xq_bf (bf16, PRE-SCALED by log2e: K-only)
// yk = y@W2 + b2 -> yk_bf (bf16) + ykT_bf (bf16 transposed)
__global__ __launch_bounds__(256, 1) void proj_kernel(
    const float* __restrict__ x, const float* __restrict__ y,
    const float* __restrict__ W1, const float* __restrict__ b1,
    const float* __restrict__ W2, const float* __restrict__ b2,
    float* __restrict__ xq_f32,
    unsigned short* __restrict__ xq_bf,
    unsigned short* __restrict__ yk_bf,
    unsigned short* __restrict__ ykT_bf)
{
    __shared__ unsigned short Xlds[64][136];
    __shared__ unsigned short Ylds[64][136];
    __shared__ unsigned short Tlds[128][72];

    const int t    = threadIdx.x;
    const int lane = t & 63;
    const int w    = t >> 6;
    const int l31  = lane & 31;
    const int g    = lane >> 5;
    const int r0   = blockIdx.x * 64;
    const int b    = r0 >> 12;
    const int j0   = r0 & (HWSZ - 1);

    #pragma unroll
    for (int i = 0; i < 8; ++i) {
        int li = t + 256 * i;
        int row = li >> 5, c = (li & 31) * 4;
        float4 vx = *(const float4*)(x + (size_t)(r0 + row) * 128 + c);
        float4 vy = *(const float4*)(y + (size_t)(r0 + row) * 128 + c);
        *(uint2*)&Xlds[row][c] = make_uint2(cvt_pk_bf16(vx.x, vx.y), cvt_pk_bf16(vx.z, vx.w));
        *(uint2*)&Ylds[row][c] = make_uint2(cvt_pk_bf16(vy.x, vy.y), cvt_pk_bf16(vy.z, vy.w));
    }
    __syncthreads();

    const int m  = w >> 1;
    const int fh = w & 1;
    const float* Wm = m ? W2 : W1;
    const float* bm = m ? b2 : b1;
    const unsigned short* A0 = m ? &Ylds[0][0] : &Xlds[0][0];

    f32x16 acc[2][2];
    #pragma unroll
    for (int i = 0; i < 16; ++i) {
        acc[0][0][i] = 0.f; acc[0][1][i] = 0.f;
        acc[1][0][i] = 0.f; acc[1][1][i] = 0.f;
    }

    #pragma unroll
    for (int ks = 0; ks < 8; ++ks) {
        s16x8 bfr[2];
        #pragma unroll
        for (int ft = 0; ft < 2; ++ft) {
            const float* wp = Wm + (size_t)(ks * 16 + g * 8) * 128 + fh * 64 + ft * 32 + l31;
            #pragma unroll
            for (int i = 0; i < 8; ++i)
                bfr[ft][i] = (short)f2bf(wp[(size_t)i * 128]);
        }
        #pragma unroll
        for (int rt = 0; rt < 2; ++rt) {
            s16x8 af = *(const s16x8*)(A0 + (size_t)(rt * 32 + l31) * 136 + ks * 16 + g * 8);
            acc[rt][0] = __builtin_amdgcn_mfma_f32_32x32x16_bf16(af, bfr[0], acc[rt][0], 0, 0, 0);
            acc[rt][1] = __builtin_amdgcn_mfma_f32_32x32x16_bf16(af, bfr[1], acc[rt][1], 0, 0, 0);
        }
    }

    const float bias_v[2] = { bm[fh * 64 + l31], bm[fh * 64 + 32 + l31] };

    if (m == 0) {
        #pragma unroll
        for (int rt = 0; rt < 2; ++rt)
        #pragma unroll
        for (int ft = 0; ft < 2; ++ft) {
            int f = fh * 64 + ft * 32 + l31;
            #pragma unroll
            for (int r = 0; r < 16; ++r) {
                int row = rt * 32 + (r & 3) + 8 * (r >> 2) + 4 * g;
                float v = acc[rt][ft][r] + bias_v[ft];
                size_t o = (size_t)(r0 + row) * 128 + f;
                xq_f32[o] = v;
                xq_bf[o]  = f2bf(v * LOG2E);      // K pre-scaled for exp2 sigmoid
            }
        }
    } else {
        #pragma unroll
        for (int rt = 0; rt < 2; ++rt)
        #pragma unroll
        for (int ft = 0; ft < 2; ++ft) {
            int f = fh * 64 + ft * 32 + l31;
            #pragma unroll
            for (int rg = 0; rg < 4; ++rg) {
                float p0 = acc[rt][ft][4 * rg + 0] + bias_v[ft];
                float p1 = acc[rt][ft][4 * rg + 1] + bias_v[ft];
                float p2 = acc[rt][ft][4 * rg + 2] + bias_v[ft];
                float p3 = acc[rt][ft][4 * rg + 3] + bias_v[ft];
                int jb = rt * 32 + 8 * rg + 4 * g;
                *(uint2*)&Tlds[f][jb] = make_uint2(cvt_pk_bf16(p0, p1), cvt_pk_bf16(p2, p3));
                size_t o = (size_t)(r0 + jb) * 128 + f;
                yk_bf[o]       = f2bf(p0);
                yk_bf[o + 128] = f2bf(p1);
                yk_bf[o + 256] = f2bf(p2);
                yk_bf[o + 384] = f2bf(p3);
            }
        }
    }
    __syncthreads();

    {
        int f  = t >> 1;
        int jh = (t & 1) * 32;
        unsigned short* dst = ykT_bf + ((size_t)(b * 128 + f)) * HWSZ + j0 + jh;
        #pragma unroll
        for (int c = 0; c < 4; ++c)
            *(s16x8*)(dst + c * 8) = *(const s16x8*)&Tlds[f][jh + c * 8];
    }
}

// ---------------- shared attention LDS geometry ----------------
#define KT_STR   136
#define VT_STR   72
#define KT_BYTES (64 * KT_STR * 2)
#define VT_BYTES (128 * VT_STR * 2)
#define BUF_BYTES (KT_BYTES + VT_BYTES)

// ---------------- Kernel 2a: QBLK=128 attention (4-way j-split) ----------------
// 4 waves = q-tiles 0..3 (each owns 32 q-rows, full 128-f output). Per staged
// 64-j tile: 2 sequential j-subtiles of {8 QK MFMA, sigmoid, shfl-exchange,
// 8 PV MFMA} => 32 MFMA per wave per barrier. No cross-wave reduction.
__global__ __launch_bounds__(256, 2) void attn128_kernel(
    const unsigned short* __restrict__ Kbf,   // xq_bf (log2e-scaled) [b][j][128]
    const unsigned short* __restrict__ Qbf,   // yk_bf  [b][q][128]
    const unsigned short* __restrict__ Vtbf,  // ykT_bf [b][128][4096]
    float* __restrict__ outp)                 // partials base (4 x NELEM)
{
    __shared__ __align__(16) char smem[2 * BUF_BYTES];

    const int t    = threadIdx.x;
    const int lane = t & 63;
    const int qt   = t >> 6;
    const int l31  = lane & 31;
    const int g    = lane >> 5;

    const int split = blockIdx.x >> 7;        // 0..3
    const int r     = blockIdx.x & 127;
    const int b     = r >> 5;
    const int qb    = (r & 31) * 128;
    const int jBegin = split * (HWSZ / 4);
    const int nt     = (HWSZ / 4) / 64;       // 16

    s16x8 qfrag[8];
    {
        const unsigned short* qp =
            Qbf + (((size_t)(b * HWSZ + qb + 32 * qt + l31)) << 7) + g * 8;
        #pragma unroll
        for (int fs = 0; fs < 8; ++fs)
            qfrag[fs] = *(const s16x8*)(qp + fs * 16);
    }

    f32x16 acc[4];
    #pragma unroll
    for (int ft = 0; ft < 4; ++ft)
        #pragma unroll
        for (int i = 0; i < 16; ++i) acc[ft][i] = 0.f;

    const unsigned short* Kbase = Kbf  + (((size_t)b * HWSZ) << 7);
    const unsigned short* Vbase = Vtbf + (((size_t)b) << 7) * HWSZ;

    const unsigned short* kSrc = Kbase + (size_t)(jBegin + (t >> 4)) * 128 + (t & 15) * 8;
    const unsigned short* vSrc = Vbase + (size_t)(t >> 3) * HWSZ + jBegin + (t & 7) * 8;
    const int kDst = (t >> 4) * KT_STR + (t & 15) * 8;
    const int vDst = (t >> 3) * VT_STR + (t & 7) * 8;

    {   // prologue: stage tile 0 into buf 0
        unsigned short* Kl = (unsigned short*)smem;
        unsigned short* Vl = (unsigned short*)(smem + KT_BYTES);
        #pragma unroll
        for (int i = 0; i < 4; ++i)
            *(s16x8*)(Kl + kDst + i * 16 * KT_STR) = *(const s16x8*)(kSrc + (size_t)i * 2048);
        #pragma unroll
        for (int i = 0; i < 4; ++i)
            *(s16x8*)(Vl + vDst + i * 32 * VT_STR) = *(const s16x8*)(vSrc + (size_t)i * 32 * HWSZ);
    }
    __syncthreads();

    int c = 0;
    for (int it = 0; it < nt; ++it) {
        const bool pre = (it + 1 < nt);
        s16x8 kr[4], vr[4];
        if (pre) {                       // issue-early loads for tile it+1
            kSrc += 64 * 128;
            vSrc += 64;
            #pragma unroll
            for (int i = 0; i < 4; ++i)
                kr[i] = *(const s16x8*)(kSrc + (size_t)i * 2048);
            #pragma unroll
            for (int i = 0; i < 4; ++i)
                vr[i] = *(const s16x8*)(vSrc + (size_t)i * 32 * HWSZ);
        }

        const unsigned short* Kl = (const unsigned short*)(smem + c * BUF_BYTES);
        const unsigned short* Vl = (const unsigned short*)(smem + c * BUF_BYTES + KT_BYTES);

        #pragma unroll
        for (int jt = 0; jt < 2; ++jt) {
            // ---- QK subtile: S'[32j][32q], dual-chain ----
            f32x16 sa, sb;
            #pragma unroll
            for (int i = 0; i < 16; ++i) { sa[i] = 0.f; sb[i] = 0.f; }
            const unsigned short* Krow = Kl + (size_t)(32 * jt + l31) * KT_STR + g * 8;
            __builtin_amdgcn_s_setprio(1);
            #pragma unroll
            for (int fs = 0; fs < 4; ++fs) {
                sa = __builtin_amdgcn_mfma_f32_32x32x16_bf16(
                         *(const s16x8*)(Krow + fs * 16), qfrag[fs], sa, 0, 0, 0);
                sb = __builtin_amdgcn_mfma_f32_32x32x16_bf16(
                         *(const s16x8*)(Krow + (fs + 4) * 16), qfrag[fs + 4], sb, 0, 0, 0);
            }
            __builtin_amdgcn_s_setprio(0);

            // ---- sigmoid via exp2 (K pre-scaled) + cvt_pk pack ----
            unsigned W0[4], W1[4];
            #pragma unroll
            for (int rg = 0; rg < 4; ++rg) {
                float s0 = sa[4 * rg + 0] + sb[4 * rg + 0];
                float s1 = sa[4 * rg + 1] + sb[4 * rg + 1];
                float s2v = sa[4 * rg + 2] + sb[4 * rg + 2];
                float s3 = sa[4 * rg + 3] + sb[4 * rg + 3];
                float p0 = __builtin_amdgcn_rcpf(1.f + __builtin_amdgcn_exp2f(-s0));
                float p1 = __builtin_amdgcn_rcpf(1.f + __builtin_amdgcn_exp2f(-s1));
                float p2 = __builtin_amdgcn_rcpf(1.f + __builtin_amdgcn_exp2f(-s2v));
                float p3 = __builtin_amdgcn_rcpf(1.f + __builtin_amdgcn_exp2f(-s3));
                W0[rg] = cvt_pk_bf16(p0, p1);
                W1[rg] = cvt_pk_bf16(p2, p3);
            }

            // ---- PV: A-frag via lane^32 exchange; ks = 2*jt + s2 ----
            #pragma unroll
            for (int s2 = 0; s2 < 2; ++s2) {
                unsigned o0 = g ? W0[2 * s2 + 1] : W0[2 * s2];
                unsigned o1 = g ? W1[2 * s2 + 1] : W1[2 * s2];
                unsigned t0 = g ? W0[2 * s2]     : W0[2 * s2 + 1];
                unsigned t1 = g ? W1[2 * s2]     : W1[2 * s2 + 1];
                unsigned r0 = __shfl_xor(t0, 32, 64);
                unsigned r1 = __shfl_xor(t1, 32, 64);
                u32x4 pw;
                pw[0] = g ? r0 : o0;
                pw[1] = g ? r1 : o1;
                pw[2] = g ? o0 : r0;
                pw[3] = g ? o1 : r1;
                s16x8 pf = __builtin_bit_cast(s16x8, pw);
                const int ks = 2 * jt + s2;
                __builtin_amdgcn_s_setprio(1);
                #pragma unroll
                for (int ft = 0; ft < 4; ++ft) {
                    s16x8 vf = *(const s16x8*)(Vl + (size_t)(32 * ft + l31) * VT_STR + ks * 16 + g * 8);
                    acc[ft] = __builtin_amdgcn_mfma_f32_32x32x16_bf16(pf, vf, acc[ft], 0, 0, 0);
                }
                __builtin_amdgcn_s_setprio(0);
            }
        }

        if (pre) {                       // write-late into other buffer
            unsigned short* Kd = (unsigned short*)(smem + (c ^ 1) * BUF_BYTES);
            unsigned short* Vd = (unsigned short*)(smem + (c ^ 1) * BUF_BYTES + KT_BYTES);
            #pragma unroll
            for (int i = 0; i < 4; ++i)
                *(s16x8*)(Kd + kDst + i * 16 * KT_STR) = kr[i];
            #pragma unroll
            for (int i = 0; i < 4; ++i)
                *(s16x8*)(Vd + vDst + i * 32 * VT_STR) = vr[i];
        }
        __syncthreads();
        c ^= 1;
    }

    // ---- epilogue: direct store of wave-private 32q x 128f partial ----
    float* op = outp + (size_t)split * ((size_t)NBATCH * HWSZ * 128);
    #pragma unroll
    for (int ft = 0; ft < 4; ++ft)
    #pragma unroll
    for (int r2 = 0; r2 < 16; ++r2) {
        int row = (r2 & 3) + 8 * (r2 >> 2) + 4 * g;
        int q = qb + 32 * qt + row;
        size_t o = (((size_t)(b * HWSZ + q)) << 7) + 32 * ft + l31;
        op[o] = acc[ft][r2];
    }
}

// ---------------- Kernel 2b: QBLK=64 fallback (2-split / no-split) ----------------
template<bool SPLIT>
__global__ __launch_bounds__(256, 2) void attn_kernel(
    const unsigned short* __restrict__ Kbf,
    const unsigned short* __restrict__ Qbf,
    const unsigned short* __restrict__ Vtbf,
    const float* __restrict__ resid,
    float* __restrict__ outp)
{
    __shared__ __align__(16) char smem[2 * BUF_BYTES];

    const int t    = threadIdx.x;
    const int lane = t & 63;
    const int w    = t >> 6;
    const int qt   = w & 1;
    const int jt   = w >> 1;
    const int l31  = lane & 31;
    const int g    = lane >> 5;

    int bid = blockIdx.x;
    int half = 0;
    if (SPLIT) { half = bid >> 8; bid &= 255; }
    const int b      = bid >> 6;
    const int qb     = (bid & 63) * 64;
    const int jBegin = half * (HWSZ / 2);
    const int nt     = (SPLIT ? HWSZ / 2 : HWSZ) / 64;

    s16x8 qfrag[8];
    {
        const unsigned short* qp =
            Qbf + (((size_t)(b * HWSZ + qb + 32 * qt + l31)) << 7) + g * 8;
        #pragma unroll
        for (int fs = 0; fs < 8; ++fs)
            qfrag[fs] = *(const s16x8*)(qp + fs * 16);
    }

    f32x16 acc[4];
    #pragma unroll
    for (int ft = 0; ft < 4; ++ft)
        #pragma unroll
        for (int i = 0; i < 16; ++i) acc[ft][i] = 0.f;

    const unsigned short* Kbase = Kbf  + (((size_t)b * HWSZ) << 7);
    const unsigned short* Vbase = Vtbf + (((size_t)b) << 7) * HWSZ;

    const unsigned short* kSrc = Kbase + (size_t)(jBegin + (t >> 4)) * 128 + (t & 15) * 8;
    const unsigned short* vSrc = Vbase + (size_t)(t >> 3) * HWSZ + jBegin + (t & 7) * 8;
    const int kDst = (t >> 4) * KT_STR + (t & 15) * 8;
    const int vDst = (t >> 3) * VT_STR + (t & 7) * 8;

    {
        unsigned short* Kl = (unsigned short*)smem;
        unsigned short* Vl = (unsigned short*)(smem + KT_BYTES);
        #pragma unroll
        for (int i = 0; i < 4; ++i)
            *(s16x8*)(Kl + kDst + i * 16 * KT_STR) = *(const s16x8*)(kSrc + (size_t)i * 2048);
        #pragma unroll
        for (int i = 0; i < 4; ++i)
            *(s16x8*)(Vl + vDst + i * 32 * VT_STR) = *(const s16x8*)(vSrc + (size_t)i * 32 * HWSZ);
    }
    __syncthreads();

    int c = 0;
    for (int it = 0; it < nt; ++it) {
        const bool pre = (it + 1 < nt);
        s16x8 kr[4], vr[4];
        if (pre) {
            kSrc += 64 * 128;
            vSrc += 64;
            #pragma unroll
            for (int i = 0; i < 4; ++i)
                kr[i] = *(const s16x8*)(kSrc + (size_t)i * 2048);
            #pragma unroll
            for (int i = 0; i < 4; ++i)
                vr[i] = *(const s16x8*)(vSrc + (size_t)i * 32 * HWSZ);
        }

        const unsigned short* Kl = (const unsigned short*)(smem + c * BUF_BYTES);
        const unsigned short* Vl = (const unsigned short*)(smem + c * BUF_BYTES + KT_BYTES);

        f32x16 sa, sb;
        #pragma unroll
        for (int i = 0; i < 16; ++i) { sa[i] = 0.f; sb[i] = 0.f; }
        const unsigned short* Krow = Kl + (size_t)(32 * jt + l31) * KT_STR + g * 8;
        __builtin_amdgcn_s_setprio(1);
        #pragma unroll
        for (int fs = 0; fs < 4; ++fs) {
            sa = __builtin_amdgcn_mfma_f32_32x32x16_bf16(
                     *(const s16x8*)(Krow + fs * 16), qfrag[fs], sa, 0, 0, 0);
            sb = __builtin_amdgcn_mfma_f32_32x32x16_bf16(
                     *(const s16x8*)(Krow + (fs + 4) * 16), qfrag[fs + 4], sb, 0, 0, 0);
        }
        __builtin_amdgcn_s_setprio(0);

        unsigned W0[4], W1[4];
        #pragma unroll
        for (int rg = 0; rg < 4; ++rg) {
            float s0 = sa[4 * rg + 0] + sb[4 * rg + 0];
            float s1 = sa[4 * rg + 1] + sb[4 * rg + 1];
            float s2v = sa[4 * rg + 2] + sb[4 * rg + 2];
            float s3 = sa[4 * rg + 3] + sb[4 * rg + 3];
            float p0 = __builtin_amdgcn_rcpf(1.f + __builtin_amdgcn_exp2f(-s0));
            float p1 = __builtin_amdgcn_rcpf(1.f + __builtin_amdgcn_exp2f(-s1));
            float p2 = __builtin_amdgcn_rcpf(1.f + __builtin_amdgcn_exp2f(-s2v));
            float p3 = __builtin_amdgcn_rcpf(1.f + __builtin_amdgcn_exp2f(-s3));
            W0[rg] = cvt_pk_bf16(p0, p1);
            W1[rg] = cvt_pk_bf16(p2, p3);
        }

        #pragma unroll
        for (int s2 = 0; s2 < 2; ++s2) {
            unsigned o0 = g ? W0[2 * s2 + 1] : W0[2 * s2];
            unsigned o1 = g ? W1[2 * s2 + 1] : W1[2 * s2];
            unsigned t0 = g ? W0[2 * s2]     : W0[2 * s2 + 1];
            unsigned t1 = g ? W1[2 * s2]     : W1[2 * s2 + 1];
            unsigned r0 = __shfl_xor(t0, 32, 64);
            unsigned r1 = __shfl_xor(t1, 32, 64);
            u32x4 pw;
            pw[0] = g ? r0 : o0;
            pw[1] = g ? r1 : o1;
            pw[2] = g ? o0 : r0;
            pw[3] = g ? o1 : r1;
            s16x8 pf = __builtin_bit_cast(s16x8, pw);
            const int ks = 2 * jt + s2;
            __builtin_amdgcn_s_setprio(1);
            #pragma unroll
            for (int ft = 0; ft < 4; ++ft) {
                s16x8 vf = *(const s16x8*)(Vl + (size_t)(32 * ft + l31) * VT_STR + ks * 16 + g * 8);
                acc[ft] = __builtin_amdgcn_mfma_f32_32x32x16_bf16(pf, vf, acc[ft], 0, 0, 0);
            }
            __builtin_amdgcn_s_setprio(0);
        }

        if (pre) {
            unsigned short* Kd = (unsigned short*)(smem + (c ^ 1) * BUF_BYTES);
            unsigned short* Vd = (unsigned short*)(smem + (c ^ 1) * BUF_BYTES + KT_BYTES);
            #pragma unroll
            for (int i = 0; i < 4; ++i)
                *(s16x8*)(Kd + kDst + i * 16 * KT_STR) = kr[i];
            #pragma unroll
            for (int i = 0; i < 4; ++i)
                *(s16x8*)(Vd + vDst + i * 32 * VT_STR) = vr[i];
        }
        __syncthreads();
        c ^= 1;
    }

    float* red = (float*)smem;
    if (jt == 1) {
        #pragma unroll
        for (int ft = 0; ft < 4; ++ft)
        #pragma unroll
        for (int r = 0; r < 16; ++r) {
            int row = (r & 3) + 8 * (r >> 2) + 4 * g;
            red[qt * 4096 + row * 128 + 32 * ft + l31] = acc[ft][r];
        }
    }
    __syncthreads();
    if (jt == 0) {
        float* op = outp + (SPLIT ? (size_t)half * ((size_t)NBATCH * HWSZ * 128) : 0);
        #pragma unroll
        for (int ft = 0; ft < 4; ++ft)
        #pragma unroll
        for (int r = 0; r < 16; ++r) {
            int row = (r & 3) + 8 * (r >> 2) + 4 * g;
            float v = acc[ft][r] + red[qt * 4096 + row * 128 + 32 * ft + l31];
            int q = qb + 32 * qt + row;
            size_t o = (((size_t)(b * HWSZ + q)) << 7) + 32 * ft + l31;
            if (SPLIT) op[o] = v;
            else       op[o] = v + resid[o];
        }
    }
}

// ---------------- Kernel 3: partial reduce + residual ----------------
__global__ __launch_bounds__(256, 1) void reduce2_kernel(
    const float* __restrict__ p0, const float* __restrict__ p1, float* outp)
{
    int i = blockIdx.x * 256 + threadIdx.x;
    f32x4 a = ((const f32x4*)p0)[i];
    f32x4 b = ((const f32x4*)p1)[i];
    f32x4 c = ((f32x4*)outp)[i];
    ((f32x4*)outp)[i] = a + b + c;
}

__global__ __launch_bounds__(256, 1) void reduce4_kernel(
    const float* __restrict__ parts, float* __restrict__ outp)
{
    const size_t NELEM4 = (size_t)NBATCH * HWSZ * 128 / 4;
    size_t i = (size_t)blockIdx.x * 256 + threadIdx.x;
    f32x4 a = ((const f32x4*)parts)[i];
    f32x4 b = ((const f32x4*)parts)[i + NELEM4];
    f32x4 c = ((const f32x4*)parts)[i + 2 * NELEM4];
    f32x4 d = ((const f32x4*)parts)[i + 3 * NELEM4];
    f32x4 e = ((f32x4*)outp)[i];          // xq residual
    ((f32x4*)outp)[i] = (a + b) + (c + d) + e;
}

extern "C" void kernel_launch(void* const* d_in, const int* in_sizes, int n_in,
                              void* d_out, int out_size, void* d_ws, size_t ws_size,
                              hipStream_t stream) {
    const float* x  = (const float*)d_in[0];
    const float* y  = (const float*)d_in[1];
    const float* W1 = (const float*)d_in[2];
    const float* b1 = (const float*)d_in[3];
    const float* W2 = (const float*)d_in[4];
    const float* b2 = (const float*)d_in[5];
    float* out = (float*)d_out;

    const size_t NELEM = (size_t)NBATCH * HWSZ * 128;   // 2,097,152
    unsigned short* xq_bf  = (unsigned short*)d_ws;
    unsigned short* yk_bf  = xq_bf + NELEM;
    unsigned short* ykT_bf = yk_bf + NELEM;
    float* part = (float*)(ykT_bf + NELEM);

    proj_kernel<<<(int)(NBATCH * HWSZ / 64), 256, 0, stream>>>(
        x, y, W1, b1, W2, b2, out, xq_bf, yk_bf, ykT_bf);

    if (ws_size >= NELEM * (6 + 16)) {               // 46.1 MB: QBLK=128, 4-split
        attn128_kernel<<<512, 256, 0, stream>>>(xq_bf, yk_bf, ykT_bf, part);
        reduce4_kernel<<<(int)(NELEM / 1024), 256, 0, stream>>>(part, out);
    } else if (ws_size >= NELEM * (6 + 8)) {         // 29.4 MB: QBLK=64, 2-split
        attn_kernel<true><<<512, 256, 0, stream>>>(xq_bf, yk_bf, ykT_bf, out, part);
        reduce2_kernel<<<(int)(NELEM / 1024), 256, 0, stream>>>(part, part + NELEM, out);
    } else {
        attn_kernel<false><<<256, 256, 0, stream>>>(xq_bf, yk_bf, ykT_bf, out, out);
    }
}